// Round 18
// baseline (733.345 us; speedup 1.0000x reference)
//
#include <hip/hip_runtime.h>
#include <hip/hip_bf16.h>

// ===========================================================================
// Decoder layer: RMSNorm -> QKV(+head RMSNorm+RoPE) -> GQA attn with R=128
// virtual KV tokens -> Wo + residual -> RMSNorm -> SwiGLU MLP -> residual.
// Round 18: k_gemm = R15 structure (256x128 tile, BK=32, 8 waves, 3 LDS
// slots, depth-2 prefetch, counted vmcnt(3), setprio) with the inner MFMA
// switched to v_mfma_f32_32x32x16_bf16 (2495 vs 2176 TF ceiling, half the
// MFMA instructions). Per-wave 64x64 = 2x2 frags of 32x32 (acc 64 VGPR).
// C/D mapping: col=lane&31, row=(reg&3)+8*(reg>>2)+4*(lane>>5)  [m74/m101].
// ===========================================================================

#define DEV __device__ __forceinline__

using f32x4  = __attribute__((ext_vector_type(4))) float;
using f32x16 = __attribute__((ext_vector_type(16))) float;
using bf16x8 = __attribute__((ext_vector_type(8))) short;

constexpr int B_ = 2, T_ = 2048, D_ = 2048, H_ = 16, HKV_ = 8, HD_ = 128;
constexpr int R_ = 128, DFF_ = 6144, TK_ = R_ + T_;   // TK_=2176
constexpr int NT64_ = TK_ / 64;                       // 34 key-tiles
constexpr int QKVW_ = 4096;                           // fused QKV row width
constexpr float EPS_ = 1e-6f;
constexpr float SCALING_ = 0.08838834764831845f;      // 128^-0.5

DEV float bf2f(unsigned short u) {
  unsigned int x = ((unsigned int)u) << 16;
  return __builtin_bit_cast(float, x);
}
DEV unsigned short f2bf(float f) {
  unsigned int x = __builtin_bit_cast(unsigned int, f);
  x += 0x7fffu + ((x >> 16) & 1u);   // RNE
  return (unsigned short)(x >> 16);
}

// async global -> LDS, 16B per lane. lds base wave-uniform; HW writes lane l
// at lds + l*16. global source address is per-lane.
DEV void gload_lds16(const void* g, void* l) {
  __builtin_amdgcn_global_load_lds((__attribute__((address_space(1))) void*)(g),
                                   (__attribute__((address_space(3))) void*)(l),
                                   16, 0, 0);
}

// ---------------------------------------------------------------------------
// RMSNorm (fp32 in, bf16 out). One block per row of D=2048, 256 thr x 8 elem.
// ---------------------------------------------------------------------------
__global__ __launch_bounds__(256) void k_rmsnorm(const float* __restrict__ x,
                                                 const float* __restrict__ w,
                                                 unsigned short* __restrict__ out) {
  const int row = blockIdx.x;
  const float* xr = x + (size_t)row * D_;
  const int t8 = threadIdx.x * 8;
  float4 a = *(const float4*)(xr + t8);
  float4 b = *(const float4*)(xr + t8 + 4);
  float ss = a.x*a.x + a.y*a.y + a.z*a.z + a.w*a.w
           + b.x*b.x + b.y*b.y + b.z*b.z + b.w*b.w;
  #pragma unroll
  for (int m = 1; m < 64; m <<= 1) ss += __shfl_xor(ss, m);
  __shared__ float red[4];
  if ((threadIdx.x & 63) == 0) red[threadIdx.x >> 6] = ss;
  __syncthreads();
  ss = red[0] + red[1] + red[2] + red[3];
  const float sc = rsqrtf(ss * (1.0f / D_) + EPS_);
  float4 wa = *(const float4*)(w + t8);
  float4 wb = *(const float4*)(w + t8 + 4);
  bf16x8 ov;
  ov[0] = (short)f2bf(a.x * sc * wa.x); ov[1] = (short)f2bf(a.y * sc * wa.y);
  ov[2] = (short)f2bf(a.z * sc * wa.z); ov[3] = (short)f2bf(a.w * sc * wa.w);
  ov[4] = (short)f2bf(b.x * sc * wb.x); ov[5] = (short)f2bf(b.y * sc * wb.y);
  ov[6] = (short)f2bf(b.z * sc * wb.z); ov[7] = (short)f2bf(b.w * sc * wb.w);
  *(bf16x8*)(out + (size_t)row * D_ + t8) = ov;
}

// ---------------------------------------------------------------------------
// Combine Wo split-K partials + residual, then RMSNorm.
// ---------------------------------------------------------------------------
__global__ __launch_bounds__(256) void k_rms2(const float* __restrict__ p0,
                                              const float* __restrict__ p1,
                                              const float* __restrict__ hs,
                                              const float* __restrict__ w,
                                              float* __restrict__ hidden,
                                              unsigned short* __restrict__ out) {
  const int row = blockIdx.x;
  const size_t base = (size_t)row * D_ + threadIdx.x * 8;
  float4 a0 = *(const float4*)(p0 + base), a1 = *(const float4*)(p0 + base + 4);
  float4 b0 = *(const float4*)(p1 + base), b1 = *(const float4*)(p1 + base + 4);
  float4 c0 = *(const float4*)(hs + base), c1 = *(const float4*)(hs + base + 4);
  float4 va, vb;
  va.x = a0.x + b0.x + c0.x; va.y = a0.y + b0.y + c0.y;
  va.z = a0.z + b0.z + c0.z; va.w = a0.w + b0.w + c0.w;
  vb.x = a1.x + b1.x + c1.x; vb.y = a1.y + b1.y + c1.y;
  vb.z = a1.z + b1.z + c1.z; vb.w = a1.w + b1.w + c1.w;
  *(float4*)(hidden + base) = va;
  *(float4*)(hidden + base + 4) = vb;
  float ss = va.x*va.x + va.y*va.y + va.z*va.z + va.w*va.w
           + vb.x*vb.x + vb.y*vb.y + vb.z*vb.z + vb.w*vb.w;
  #pragma unroll
  for (int m = 1; m < 64; m <<= 1) ss += __shfl_xor(ss, m);
  __shared__ float red[4];
  if ((threadIdx.x & 63) == 0) red[threadIdx.x >> 6] = ss;
  __syncthreads();
  ss = red[0] + red[1] + red[2] + red[3];
  const float sc = rsqrtf(ss * (1.0f / D_) + EPS_);
  const int t8 = threadIdx.x * 8;
  float4 wa = *(const float4*)(w + t8);
  float4 wb = *(const float4*)(w + t8 + 4);
  bf16x8 ov;
  ov[0] = (short)f2bf(va.x * sc * wa.x); ov[1] = (short)f2bf(va.y * sc * wa.y);
  ov[2] = (short)f2bf(va.z * sc * wa.z); ov[3] = (short)f2bf(va.w * sc * wa.w);
  ov[4] = (short)f2bf(vb.x * sc * wb.x); ov[5] = (short)f2bf(vb.y * sc * wb.y);
  ov[6] = (short)f2bf(vb.z * sc * wb.z); ov[7] = (short)f2bf(vb.w * sc * wb.w);
  *(bf16x8*)(out + (size_t)row * D_ + t8) = ov;
}

// ---------------------------------------------------------------------------
// Final: d_out = p0 + p1 + hidden  (Wd split-K combine + residual), float4.
// ---------------------------------------------------------------------------
__global__ __launch_bounds__(256) void k_finaladd(const float* __restrict__ p0,
                                                  const float* __restrict__ p1,
                                                  const float* __restrict__ hidden,
                                                  float* __restrict__ out) {
  const size_t i = ((size_t)blockIdx.x * 256 + threadIdx.x) * 4;
  float4 a = *(const float4*)(p0 + i);
  float4 b = *(const float4*)(p1 + i);
  float4 c = *(const float4*)(hidden + i);
  float4 o;
  o.x = a.x + b.x + c.x; o.y = a.y + b.y + c.y;
  o.z = a.z + b.z + c.z; o.w = a.w + b.w + c.w;
  *(float4*)(out + i) = o;
}

// ---------------------------------------------------------------------------
// Weight transpose+convert: W (K,N) fp32 row-major -> Wt (N,K) bf16 row-major.
// ---------------------------------------------------------------------------
__global__ __launch_bounds__(256) void k_wtrans(const float* __restrict__ W,
                                                unsigned short* __restrict__ Wt,
                                                int K, int N) {
  __shared__ float tile[32][33];
  const int n0 = blockIdx.x * 32, k0 = blockIdx.y * 32;
  {
    const int kl = threadIdx.x >> 3, nc = (threadIdx.x & 7) * 4;
    float4 f = *(const float4*)(W + (size_t)(k0 + kl) * N + n0 + nc);
    tile[kl][nc] = f.x; tile[kl][nc + 1] = f.y;
    tile[kl][nc + 2] = f.z; tile[kl][nc + 3] = f.w;
  }
  __syncthreads();
  const int nl = threadIdx.x >> 3, kc = (threadIdx.x & 7) * 4;
  ushort4 o;
  o.x = f2bf(tile[kc][nl]);     o.y = f2bf(tile[kc + 1][nl]);
  o.z = f2bf(tile[kc + 2][nl]); o.w = f2bf(tile[kc + 3][nl]);
  *(ushort4*)(Wt + (size_t)(n0 + nl) * K + k0 + kc) = o;
}

// ---------------------------------------------------------------------------
// GEMM: C(M,N) = A(M,K) @ Bt(N,K)^T, bf16 in, fp32 accum.
// 256x128 tile, BK=32, 512 thr (8 waves 4x2), per-wave 64x64 out via 2x2
// frags of 32x32 (v_mfma_f32_32x32x16_bf16, acc f32x16[2][2]). 3 LDS slots
// x 24KB; depth-2 prefetch, counted vmcnt(3), ONE barrier per K-step;
// ds_read -> MFMA waits left to the compiler; setprio around MFMA cluster.
// T2 swizzle via pre-swizzled global source (staging identical to R15);
// read: phys colbyte = logical ^ ((row>>1)&3)<<4. GROUP_M=4.
// A/B operands use identical (lane,elem)->k addressing (k-perm invariant).
// EPI=0: bf16 out. EPI=2: bf16 = silu(gmul)*acc. EPI=3: fp32 partial (splitK).
// ---------------------------------------------------------------------------
template <int EPI>
__global__ __launch_bounds__(512, 4) void k_gemm(const unsigned short* __restrict__ A,
                                                 const unsigned short* __restrict__ Bt,
                                                 void* __restrict__ Cp,
                                                 const unsigned short* __restrict__ gmul,
                                                 int M, int ldc, int K) {
  __shared__ __align__(16) char lds[3 * 24576];   // slot s: A@s*24576 (16KB), B@+16384 (8KB)
  const int tid = threadIdx.x, lane = tid & 63, wave = tid >> 6;
  const int wm = wave >> 1, wn = wave & 1;

  // tile mapping: XCD bijective chunk + GROUP_M=4 column-major groups.
  const int nbx = (int)gridDim.x;
  const int nwg = nbx * (int)gridDim.y;
  int bid = (int)blockIdx.y * nbx + (int)blockIdx.x;
  bid = (bid & 7) * (nwg >> 3) + (bid >> 3);
  const int glen = 4 * nbx;
  const int gid = bid / glen, rem = bid - gid * glen;
  const int row0 = (gid * 4 + (rem & 3)) * 256;
  const int col0 = (rem >> 2) * 128;

  const int kz = (int)blockIdx.z;
  const int Klocal = K / (int)gridDim.z;
  const int kbeg = kz * Klocal;
  const int NK = Klocal / 32;

  // staging map (identical to R15): A call i in {0,1}: LDS byte i*8192 +
  // wave*1024 + l*16 -> row r = i*128 + wave*16 + (l>>2), phys col (l&3)*16;
  // B one call rows 0..127. Logical k-elem pre-XORed (T2 swizzle).
  const int srow = wave * 16 + (lane >> 2);
  const int selem = (((lane & 3) ^ ((lane >> 3) & 3)) << 3);
  const unsigned short* pa = A  + (size_t)(row0 + srow) * K + kbeg + selem;
  const unsigned short* pb = Bt + (size_t)(col0 + srow) * K + kbeg + selem;
  const size_t rstep = (size_t)128 * K;
  char* const l = (char*)lds;
  const int woff = wave * 1024;

  f32x16 acc[2][2];
  #pragma unroll
  for (int i = 0; i < 2; i++)
    #pragma unroll
    for (int j = 0; j < 2; j++)
      #pragma unroll
      for (int e = 0; e < 16; e++) acc[i][j][e] = 0.f;

  auto STAGE = [&](int t, int slot) {
    char* s = l + slot * 24576;
    const unsigned short* a = pa + (size_t)t * 32;
    const unsigned short* b = pb + (size_t)t * 32;
    gload_lds16(a,         s + woff);
    gload_lds16(a + rstep, s + 8192 + woff);
    gload_lds16(b,         s + 16384 + woff);
  };

  // prologue: stage tiles 0,1 (3 loads each)
  STAGE(0, 0);
  STAGE(1, 1);

  // fragment read addressing: row = base + (lane&31); logical colbyte =
  // kk*32 + (lane>>5)*16; phys = logical ^ ((row>>1)&3)<<4, (row>>1)&3 ==
  // (lane>>1)&3 (frag row-bases are multiples of 32).
  const int aswz = ((lane >> 1) & 3) << 4;
  const int khi = (lane >> 5) << 4;
  const int arow0 = wm * 64 + (lane & 31);
  const int brow0 = wn * 64 + (lane & 31);

  int cur = 0, stg = 2;   // read slot = t%3, stage slot = (t+2)%3
  for (int t = 0; t < NK; ++t) {
    if (t + 2 < NK) {
      asm volatile("s_waitcnt vmcnt(3)" ::: "memory");   // STAGE(t) landed
    } else {
      asm volatile("s_waitcnt vmcnt(0)" ::: "memory");   // tail: drain all
    }
    __builtin_amdgcn_sched_barrier(0);
    __builtin_amdgcn_s_barrier();   // all waves: STAGE(t) landed; reads of
                                    // slot (t+2)%3 (iter t-1) retired.
    __builtin_amdgcn_sched_barrier(0);   // no hoisting reads above barrier
    const char* sa = l + cur * 24576;
    const char* sb = sa + 16384;
    bf16x8 af[2][2], bfr[2][2];   // [kk][mi/ni]
    #pragma unroll
    for (int kk = 0; kk < 2; kk++)
      #pragma unroll
      for (int i = 0; i < 2; i++) {
        af[kk][i]  = *(const bf16x8*)(sa + (arow0 + i * 32) * 64 + ((kk * 32 + khi) ^ aswz));
        bfr[kk][i] = *(const bf16x8*)(sb + (brow0 + i * 32) * 64 + ((kk * 32 + khi) ^ aswz));
      }
    if (t + 2 < NK) STAGE(t + 2, stg);
    // ds_read -> MFMA waits: compiler-inserted fine-grained lgkmcnt.
    __builtin_amdgcn_s_setprio(1);
    #pragma unroll
    for (int kk = 0; kk < 2; kk++)
      #pragma unroll
      for (int mi = 0; mi < 2; mi++)
        #pragma unroll
        for (int ni = 0; ni < 2; ni++)
          acc[mi][ni] = __builtin_amdgcn_mfma_f32_32x32x16_bf16(af[kk][mi], bfr[kk][ni],
                                                                acc[mi][ni], 0, 0, 0);
    __builtin_amdgcn_s_setprio(0);
    cur = (cur == 2) ? 0 : cur + 1;
    stg = (stg == 2) ? 0 : stg + 1;
  }

  // epilogue: C/D layout (m74/m101): col = lane&31,
  // row = (reg&3) + 8*(reg>>2) + 4*(lane>>5), reg in [0,16).
  const int crow = row0 + wm * 64 + 4 * (lane >> 5);
  const int ccol = col0 + wn * 64 + (lane & 31);
  #pragma unroll
  for (int mi = 0; mi < 2; mi++)
    #pragma unroll
    for (int ni = 0; ni < 2; ni++) {
      #pragma unroll
      for (int j = 0; j < 16; j++) {
        const int r = crow + mi * 32 + (j & 3) + 8 * (j >> 2);
        const int c = ccol + ni * 32;
        if constexpr (EPI == 0) {
          ((unsigned short*)Cp)[(size_t)r * ldc + c] = f2bf(acc[mi][ni][j]);
        } else if constexpr (EPI == 2) {
          const float gx = bf2f(gmul[(size_t)r * ldc + c]);
          ((unsigned short*)Cp)[(size_t)r * ldc + c] =
              f2bf(gx / (1.f + __expf(-gx)) * acc[mi][ni][j]);
        } else {
          ((float*)Cp + (size_t)kz * M * ldc)[(size_t)r * ldc + c] = acc[mi][ni][j];
        }
      }
    }
}

// ---------------------------------------------------------------------------
// Per-head RMSNorm + RoPE from the fused QKV buffer (row stride 4096).
// ---------------------------------------------------------------------------
template <int ISQ>
__global__ __launch_bounds__(256) void k_qknorm(const unsigned short* __restrict__ qkv,
                                                const float* __restrict__ nw,
                                                const float* __restrict__ cosT,
                                                const float* __restrict__ sinT,
                                                unsigned short* __restrict__ out) {
  const int NH = ISQ ? H_ : HKV_;
  const int HOFF = ISQ ? 0 : H_;
  const int r = blockIdx.x * 16 + (threadIdx.x >> 4);
  const int l16 = threadIdx.x & 15;
  const int hd0 = l16 * 8;
  const int b = r / (T_ * NH), rem = r % (T_ * NH);
  const int t = rem / NH, hh = rem % NH;
  bf16x8 v = *(const bf16x8*)(qkv + (size_t)(b * T_ + t) * QKVW_ + (HOFF + hh) * HD_ + hd0);
  float f[8];
  float ss = 0.f;
  #pragma unroll
  for (int j = 0; j < 8; j++) { f[j] = bf2f((unsigned short)v[j]); ss += f[j] * f[j]; }
  #pragma unroll
  for (int m = 1; m < 16; m <<= 1) ss += __shfl_xor(ss, m);
  const float sc = rsqrtf(ss * (1.0f / HD_) + EPS_);
  float4 wa = *(const float4*)(nw + hd0);
  float4 wb = *(const float4*)(nw + hd0 + 4);
  float nv[8];
  nv[0] = f[0] * sc * wa.x; nv[1] = f[1] * sc * wa.y;
  nv[2] = f[2] * sc * wa.z; nv[3] = f[3] * sc * wa.w;
  nv[4] = f[4] * sc * wb.x; nv[5] = f[5] * sc * wb.y;
  nv[6] = f[6] * sc * wb.z; nv[7] = f[7] * sc * wb.w;
  const float sgn = (hd0 < 64) ? -1.f : 1.f;
  float rot[8];
  #pragma unroll
  for (int j = 0; j < 8; j++) rot[j] = sgn * __shfl_xor(nv[j], 8);
  const float* cr = cosT + (size_t)t * HD_ + hd0;
  const float* sr = sinT + (size_t)t * HD_ + hd0;
  float4 ca = *(const float4*)cr, cb = *(const float4*)(cr + 4);
  float4 sa = *(const float4*)sr, sb = *(const float4*)(sr + 4);
  const float cv[8] = {ca.x, ca.y, ca.z, ca.w, cb.x, cb.y, cb.z, cb.w};
  const float sv[8] = {sa.x, sa.y, sa.z, sa.w, sb.x, sb.y, sb.z, sb.w};
  bf16x8 ov;
  #pragma unroll
  for (int j = 0; j < 8; j++) ov[j] = (short)f2bf(nv[j] * cv[j] + rot[j] * sv[j]);
  if (ISQ) *(bf16x8*)(out + (((size_t)b * H_ + hh) * T_ + t) * HD_ + hd0) = ov;
  else     *(bf16x8*)(out + (((size_t)b * HKV_ + hh) * TK_ + R_ + t) * HD_ + hd0) = ov;
}

// ---------------------------------------------------------------------------
// Virtual K rows: k_all[.., 0..R-1, ..] = k_extra * eff  (eff = 0.5*sigmoid(a))
// ---------------------------------------------------------------------------
__global__ __launch_bounds__(256) void k_kvirt(const float* __restrict__ ke,
                                               const float* __restrict__ alog,
                                               unsigned short* __restrict__ k_all) {
  const size_t i = (size_t)blockIdx.x * 256 + threadIdx.x;  // B*HKV*R*HD = 262144
  const float eff = 0.5f / (1.f + __expf(-alog[0]));
  const int hd = (int)(i & 127);
  const int r  = (int)((i >> 7) & 127);
  const int bk = (int)(i >> 14);
  k_all[((size_t)bk * TK_ + r) * HD_ + hd] = f2bf(ke[i] * eff);
}

// ---------------------------------------------------------------------------
// Build v_allT, key-tiled: (B,HKV, NT64, HD, 64key) bf16 from [v_extra*eff ; v].
// Key columns inside each 64-tile PERMUTED to the PV register k-order.
// ---------------------------------------------------------------------------
__global__ __launch_bounds__(256) void k_vbuild(const unsigned short* __restrict__ qkv,
                                                const float* __restrict__ ve,
                                                const float* __restrict__ alog,
                                                unsigned short* __restrict__ vT) {
  __shared__ float tile[32][33];
  const int kt = blockIdx.x, ht = blockIdx.y, bk = blockIdx.z;
  const int b = bk >> 3, kvh = bk & 7;
  const float eff = 0.5f / (1.f + __expf(-alog[0]));
  const int kl = threadIdx.x >> 3, hc = (threadIdx.x & 7) * 4;
  const int key = kt * 32 + kl, hd0 = ht * 32;
  if (key < R_) {
    float4 f = *(const float4*)(ve + (((size_t)(b * HKV_ + kvh) * R_ + key) * HD_ + hd0 + hc));
    tile[kl][hc] = f.x * eff; tile[kl][hc + 1] = f.y * eff;
    tile[kl][hc + 2] = f.z * eff; tile[kl][hc + 3] = f.w * eff;
  } else {
    const unsigned short* s = qkv + (size_t)(b * T_ + key - R_) * QKVW_
                              + (H_ + HKV_ + kvh) * HD_ + hd0 + hc;
    ushort4 u = *(const ushort4*)s;
    tile[kl][hc] = bf2f(u.x); tile[kl][hc + 1] = bf2f(u.y);
    tile[kl][hc + 2] = bf2f(u.z); tile[kl][hc + 3] = bf2f(u.w);
  }
  __syncthreads();
  const int hl = threadIdx.x >> 3, kc = (threadIdx.x & 7) * 4;
  ushort4 o;
  o.x = f2bf(tile[kc][hl]);     o.y = f2bf(tile[kc + 1][hl]);
  o.z = f2bf(tile[kc + 2][hl]); o.w = f2bf(tile[kc + 3][hl]);
  const int c0 = (kt & 1) * 32 + kc;
  const int p0 = ((c0 >> 5) << 5) | (((c0 >> 2) & 3) << 3) | (((c0 >> 4) & 1) << 2);
  *(ushort4*)(vT + ((size_t)bk * NT64_ + (kt >> 1)) * (HD_ * 64)
                  + (size_t)(hd0 + hl) * 64 + p0) = o;
}

// ---------------------------------------------------------------------------
// Flash attention. 256 thr (4 waves), 128 q-rows/block (32/wave), 64-key tiles.
// Swapped QK^T; P stays in registers; double-buffered K/V via global_load_lds.
// ---------------------------------------------------------------------------
__global__ __launch_bounds__(256, 2) void k_attn(const unsigned short* __restrict__ qr,
                                                 const unsigned short* __restrict__ k_all,
                                                 const unsigned short* __restrict__ vT,
                                                 unsigned short* __restrict__ out) {
  __shared__ __align__(16) unsigned short kT[2][64 * 128];
  __shared__ __align__(16) unsigned short vS[2][128 * 64];
  const int tid = threadIdx.x, lane = tid & 63, w = tid >> 6;
  const int qb = (int)gridDim.x - 1 - (int)blockIdx.x;
  const int h = blockIdx.y, b = blockIdx.z;
  const int kvh = h >> 1;
  const int q0 = qb * 128;

  bf16x8 qf[2][4];
  #pragma unroll
  for (int fq = 0; fq < 2; fq++) {
    const unsigned short* qbase =
        qr + ((size_t)((b * H_ + h) * T_) + q0 + w * 32 + fq * 16 + (lane & 15)) * HD_ + (lane >> 4) * 8;
    #pragma unroll
    for (int kc = 0; kc < 4; kc++) qf[fq][kc] = *(const bf16x8*)(qbase + kc * 32);
  }

  f32x4 zero = {0.f, 0.f, 0.f, 0.f};
  f32x4 o[2][8];
  #pragma unroll
  for (int fq = 0; fq < 2; fq++)
    #pragma unroll
    for (int i = 0; i < 8; i++) o[fq][i] = zero;
  float mrow[2] = {-3e38f, -3e38f}, lrow[2] = {0.f, 0.f};

  const int kr0 = w * 4 + (lane >> 4);
  const char* kSrc = (const char*)(k_all + (size_t)(b * HKV_ + kvh) * TK_ * HD_)
                     + (size_t)kr0 * 256 + (((lane & 15) * 16) ^ ((kr0 & 7) << 4));
  const char* vSrc = (const char*)(vT + (size_t)(b * HKV_ + kvh) * NT64_ * HD_ * 64)
                     + (size_t)(w * 8 + (lane >> 3)) * 128
                     + (((lane & 7) * 16) ^ (((lane >> 3) & 7) << 4));
  char* kL = (char*)kT;
  char* vL = (char*)vS;
  const int ldsw = w * 1024;

  const int ntiles = 2 * qb + 4;
  #pragma unroll
  for (int i = 0; i < 4; i++) {
    gload_lds16(kSrc + i * 4096, kL + ldsw + i * 4096);
    gload_lds16(vSrc + i * 4096, vL + ldsw + i * 4096);
  }
  int cur = 0;

  for (int it = 0; it < ntiles; ++it) {
    __syncthreads();
    if (it + 1 < ntiles) {
      const char* ks = kSrc + (size_t)(it + 1) * 16384;
      const char* vs = vSrc + (size_t)(it + 1) * 16384;
      char* kd = kL + ((cur ^ 1) * 16384 + ldsw);
      char* vd = vL + ((cur ^ 1) * 16384 + ldsw);
      #pragma unroll
      for (int i = 0; i < 4; i++) {
        gload_lds16(ks + i * 4096, kd + i * 4096);
        gload_lds16(vs + i * 4096, vd + i * 4096);
      }
    }
    const char* kTc = kL + cur * 16384;
    const char* vSc = vL + cur * 16384;

    f32x4 s[2][4];
    #pragma unroll
    for (int ni = 0; ni < 4; ni++) { s[0][ni] = zero; s[1][ni] = zero; }
    #pragma unroll
    for (int ni = 0; ni < 4; ni++) {
      const int rk = ni * 16 + (lane & 15);
      const int swz = (rk & 7) << 4;
      #pragma unroll
      for (int kc = 0; kc < 4; kc++) {
        bf16x8 kf = *(const bf16x8*)(kTc + ((rk * 256 + kc * 64 + (lane >> 4) * 16) ^ swz));
        s[0][ni] = __builtin_amdgcn_mfma_f32_16x16x32_bf16(kf, qf[0][kc], s[0][ni], 0, 0, 0);
        s[1][ni] = __builtin_amdgcn_mfma_f32_16x16x32_bf16(kf, qf[1][kc], s[1][ni], 0, 0, 0);
      }
    }

    const bool domask = (it >= ntiles - 2);
    bf16x8 pa[2][2];
    #pragma unroll
    for (int fq = 0; fq < 2; fq++) {
      const int q = q0 + w * 32 + fq * 16 + (lane & 15);
      #pragma unroll
      for (int ni = 0; ni < 4; ni++)
        #pragma unroll
        for (int j = 0; j < 4; j++) {
          float v = s[fq][ni][j] * SCALING_;
          if (domask) {
            const int key = it * 64 + ni * 16 + (lane >> 4) * 4 + j;
            if (key > R_ + q) v = -3e38f;
          }
          s[fq][ni][j] = v;
        }
      float pm = -3e38f;
      #pragma unroll
      for (int ni = 0; ni < 4; ni++)
        #pragma unroll
        for (int j = 0; j < 4; j++) pm = fmaxf(pm, s[fq][ni][j]);
      pm = fmaxf(pm, __shfl_xor(pm, 16));
      pm = fmaxf(pm, __shfl_xor(pm, 32));
      const float mn = fmaxf(mrow[fq], pm);
      const float scl = __expf(mrow[fq] - mn);
      mrow[fq] = mn;
      float rs = 0.f;
      #pragma unroll
      for (int ni = 0; ni < 4; ni++)
        #pragma unroll
        for (int j = 0; j < 4; j++) {
          const float p = __expf(s[fq][ni][j] - mn);
          s[fq][ni][j] = p;
          rs += p;
        }
      rs += __shfl_xor(rs, 16);
      rs += __shfl_xor(rs, 32);
      lrow[fq] = lrow[fq] * scl + rs;
      #pragma unroll
      for (int kc2 = 0; kc2 < 2; kc2++) {
        bf16x8 t;
        #pragma unroll
        for (int j = 0; j < 4; j++) {
          t[j]     = (short)f2bf(s[fq][2 * kc2][j]);
          t[4 + j] = (short)f2bf(s[fq][2 * kc2 + 1][j]);
        }
        pa[fq][kc2] = t;
      }
      #pragma unroll
      for (int j = 0; j < 4; j++) {
        const float sj = __shfl(scl, (lane & 48) | (((lane >> 4) << 2) + j));
        #pragma unroll
        for (int ni = 0; ni < 8; ni++) o[fq][ni][j] *= sj;
      }
    }

    #pragma unroll
    for (int kc2 = 0; kc2 < 2; kc2++) {
      #pragma unroll
      for (int ni = 0; ni < 8; ni++) {
        const int rv = ni * 16 + (lane & 15);
        bf16x8 vb = *(const bf16x8*)(vSc + ((rv * 128 + kc2 * 64 + (lane >> 4) * 16) ^ ((rv & 7) << 4)));
        o[0][ni] = __builtin_amdgcn_mfma_f32_16x16x32_bf16(pa[0][kc2], vb, o[0][ni], 0, 0, 0);
        o[1][ni] = __builtin_amdgcn_mfma_f32_16x16x32_bf16(pa[1][kc2], vb, o[1][ni], 0, 0, 0);
      }
    }
    cur ^= 1;
  }

  #pragma unroll
  for (int fq = 0; fq < 2; fq++) {
    float linv[4];
    #pragma unroll
    for (int j = 0; j < 4; j++)
      linv[j] = 1.f / __shfl(lrow[fq], (lane & 48) | (((lane >> 4) << 2) + j));
    const size_t orow = ((size_t)b * T_ + q0 + w * 32 + fq * 16 + (lane >> 4) * 4) * (H_ * HD_)
                        + h * HD_ + (lane & 15);
    #pragma unroll
    for (int ni = 0; ni < 8; ni++)
      #pragma unroll
      for (int j = 0; j < 4; j++)
        out[orow + (size_t)j * (H_ * HD_) + ni * 16] = f2bf(o[fq][ni][j] * linv[j]);
  }
}

// ===========================================================================
extern "C" void kernel_launch(void* const* d_in, const int* in_sizes, int n_in,
                              void* d_out, int out_size, void* d_ws, size_t ws_size,
                              hipStream_t stream) {
  const float* hs   = (const float*)d_in[0];
  const float* ke   = (const float*)d_in[1];
  const float* ve   = (const float*)d_in[2];
  const float* cosT = (const float*)d_in[3];
  const float* sinT = (const float*)d_in[4];
  // d_in[5] = attention_mask: deterministic causal, applied analytically.
  const float* alog = (const float*)d_in[6];
  const float* Wq   = (const float*)d_in[7];
  const float* Wk   = (const float*)d_in[8];
  const float* Wv   = (const float*)d_in[9];
  const float* Wo   = (const float*)d_in[10];
  const float* qnw  = (const float*)d_in[11];
  const float* knw  = (const float*)d_in[12];
  const float* ln1  = (const float*)d_in[13];
  const float* ln2  = (const float*)d_in[14];
  const float* Wg   = (const float*)d_in[15];
  const float* Wu   = (const float*)d_in[16];
  const float* Wd   = (const float*)d_in[17];

  char* ws = (char*)d_ws;
  size_t off = 0;
  auto alloc = [&](size_t bytes) {
    void* p = ws + off;
    off += (bytes + 255) & ~(size_t)255;
    return p;
  };
  const int M = B_ * T_;  // 4096
  unsigned short* h     = (unsigned short*)alloc((size_t)M * D_ * 2);
  unsigned short* wt    = (unsigned short*)alloc((size_t)DFF_ * D_ * 2);
  unsigned short* qkv   = (unsigned short*)alloc((size_t)M * QKVW_ * 2);
  unsigned short* qrope = (unsigned short*)alloc((size_t)B_ * H_ * T_ * HD_ * 2);
  unsigned short* kall  = (unsigned short*)alloc((size_t)B_ * HKV_ * TK_ * HD_ * 2);
  unsigned short* vallT = (unsigned short*)alloc((size_t)B_ * HKV_ * (size_t)NT64_ * HD_ * 64 * 2);
  unsigned short* attno = (unsigned short*)alloc((size_t)M * 2048 * 2);
  float*          hidden= (float*)alloc((size_t)M * D_ * 4);
  unsigned short* g     = (unsigned short*)alloc((size_t)M * DFF_ * 2);
  // split-K partial stack (2 x M x 2048 fp32 = 67.1M), aliasing dead buffers.
  float* part = (float*)qkv;

  // 1) input layernorm
  k_rmsnorm<<<M, 256, 0, stream>>>(hs, ln1, h);
  // 2) fused QKV projection (N=4096)
  k_wtrans<<<dim3(2048 / 32, 2048 / 32), 256, 0, stream>>>(Wq, wt, 2048, 2048);
  k_wtrans<<<dim3(1024 / 32, 2048 / 32), 256, 0, stream>>>(Wk, wt + (size_t)2048 * 2048, 2048, 1024);
  k_wtrans<<<dim3(1024 / 32, 2048 / 32), 256, 0, stream>>>(Wv, wt + (size_t)3072 * 2048, 2048, 1024);
  k_gemm<0><<<dim3(QKVW_ / 128, M / 256), 512, 0, stream>>>(h, wt, qkv, nullptr, M, QKVW_, 2048);
  // 3) head norms + RoPE + virtual KV
  k_qknorm<1><<<(B_ * T_ * H_) / 16, 256, 0, stream>>>(qkv, qnw, cosT, sinT, qrope);
  k_qknorm<0><<<(B_ * T_ * HKV_) / 16, 256, 0, stream>>>(qkv, knw, cosT, sinT, kall);
  k_kvirt<<<(B_ * HKV_ * R_ * HD_) / 256, 256, 0, stream>>>(ke, alog, kall);
  k_vbuild<<<dim3(TK_ / 32, HD_ / 32, B_ * HKV_), 256, 0, stream>>>(qkv, ve, alog, vallT);
  // 4) attention
  k_attn<<<dim3(T_ / 128, H_, B_), 256, 0, stream>>>(qrope, kall, vallT, attno);
  // 5) output projection, split-K=2 -> fp32 partials
  k_wtrans<<<dim3(2048 / 32, 2048 / 32), 256, 0, stream>>>(Wo, wt, 2048, 2048);
  k_gemm<3><<<dim3(2048 / 128, M / 256, 2), 512, 0, stream>>>(attno, wt, part, nullptr, M, 2048, 2048);
  // 6) combine partials + residual + post-attn layernorm
  k_rms2<<<M, 256, 0, stream>>>(part, part + (size_t)M * 2048, hs, ln2, hidden, h);
  // 7) SwiGLU MLP (silu*u fused into the Wu GEMM epilogue)
  k_wtrans<<<dim3(DFF_ / 32, 2048 / 32), 256, 0, stream>>>(Wg, wt, 2048, DFF_);
  k_gemm<0><<<dim3(DFF_ / 128, M / 256), 512, 0, stream>>>(h, wt, g, nullptr, M, DFF_, 2048);
  k_wtrans<<<dim3(DFF_ / 32, 2048 / 32), 256, 0, stream>>>(Wu, wt, 2048, DFF_);
  k_gemm<2><<<dim3(DFF_ / 128, M / 256), 512, 0, stream>>>(h, wt, g, g, M, DFF_, 2048);
  // 8) down projection, split-K=2 -> partials; final add with residual
  k_wtrans<<<dim3(2048 / 32, DFF_ / 32), 256, 0, stream>>>(Wd, wt, DFF_, 2048);
  k_gemm<3><<<dim3(2048 / 128, M / 256, 2), 512, 0, stream>>>(g, wt, part, nullptr, M, 2048, DFF_);
  k_finaladd<<<(M * 2048 / 4) / 256, 256, 0, stream>>>(part, part + (size_t)M * 2048, hidden, (float*)d_out);
}

// Round 19
// 683.922 us; speedup vs baseline: 1.0723x; 1.0723x over previous
//
#include <hip/hip_runtime.h>
#include <hip/hip_bf16.h>

// ===========================================================================
// Decoder layer: RMSNorm -> QKV(+head RMSNorm+RoPE) -> GQA attn with R=128
// virtual KV tokens -> Wo + residual -> RMSNorm -> SwiGLU MLP -> residual.
// Round 19: consolidation to the session's best measured configuration
// (= round 15): k_gemm 256x128 tile, BK=32, 8 waves, 3 LDS slots, depth-2
// prefetch with counted vmcnt(3), GROUP_M=4, setprio around MFMA,
// conflict-free T2 swizzle, launch_bounds(512,4). 16x16x32 MFMA (the 32x32
// variant measured worse: swizzle gives only 4-way spread for its reads).
// ===========================================================================

#define DEV __device__ __forceinline__

using f32x4  = __attribute__((ext_vector_type(4))) float;
using bf16x8 = __attribute__((ext_vector_type(8))) short;

constexpr int B_ = 2, T_ = 2048, D_ = 2048, H_ = 16, HKV_ = 8, HD_ = 128;
constexpr int R_ = 128, DFF_ = 6144, TK_ = R_ + T_;   // TK_=2176
constexpr int NT64_ = TK_ / 64;                       // 34 key-tiles
constexpr int QKVW_ = 4096;                           // fused QKV row width
constexpr float EPS_ = 1e-6f;
constexpr float SCALING_ = 0.08838834764831845f;      // 128^-0.5

DEV float bf2f(unsigned short u) {
  unsigned int x = ((unsigned int)u) << 16;
  return __builtin_bit_cast(float, x);
}
DEV unsigned short f2bf(float f) {
  unsigned int x = __builtin_bit_cast(unsigned int, f);
  x += 0x7fffu + ((x >> 16) & 1u);   // RNE
  return (unsigned short)(x >> 16);
}

// async global -> LDS, 16B per lane. lds base wave-uniform; HW writes lane l
// at lds + l*16. global source address is per-lane.
DEV void gload_lds16(const void* g, void* l) {
  __builtin_amdgcn_global_load_lds((__attribute__((address_space(1))) void*)(g),
                                   (__attribute__((address_space(3))) void*)(l),
                                   16, 0, 0);
}

// ---------------------------------------------------------------------------
// RMSNorm (fp32 in, bf16 out). One block per row of D=2048, 256 thr x 8 elem.
// ---------------------------------------------------------------------------
__global__ __launch_bounds__(256) void k_rmsnorm(const float* __restrict__ x,
                                                 const float* __restrict__ w,
                                                 unsigned short* __restrict__ out) {
  const int row = blockIdx.x;
  const float* xr = x + (size_t)row * D_;
  const int t8 = threadIdx.x * 8;
  float4 a = *(const float4*)(xr + t8);
  float4 b = *(const float4*)(xr + t8 + 4);
  float ss = a.x*a.x + a.y*a.y + a.z*a.z + a.w*a.w
           + b.x*b.x + b.y*b.y + b.z*b.z + b.w*b.w;
  #pragma unroll
  for (int m = 1; m < 64; m <<= 1) ss += __shfl_xor(ss, m);
  __shared__ float red[4];
  if ((threadIdx.x & 63) == 0) red[threadIdx.x >> 6] = ss;
  __syncthreads();
  ss = red[0] + red[1] + red[2] + red[3];
  const float sc = rsqrtf(ss * (1.0f / D_) + EPS_);
  float4 wa = *(const float4*)(w + t8);
  float4 wb = *(const float4*)(w + t8 + 4);
  bf16x8 ov;
  ov[0] = (short)f2bf(a.x * sc * wa.x); ov[1] = (short)f2bf(a.y * sc * wa.y);
  ov[2] = (short)f2bf(a.z * sc * wa.z); ov[3] = (short)f2bf(a.w * sc * wa.w);
  ov[4] = (short)f2bf(b.x * sc * wb.x); ov[5] = (short)f2bf(b.y * sc * wb.y);
  ov[6] = (short)f2bf(b.z * sc * wb.z); ov[7] = (short)f2bf(b.w * sc * wb.w);
  *(bf16x8*)(out + (size_t)row * D_ + t8) = ov;
}

// ---------------------------------------------------------------------------
// Combine Wo split-K partials + residual, then RMSNorm.
// ---------------------------------------------------------------------------
__global__ __launch_bounds__(256) void k_rms2(const float* __restrict__ p0,
                                              const float* __restrict__ p1,
                                              const float* __restrict__ hs,
                                              const float* __restrict__ w,
                                              float* __restrict__ hidden,
                                              unsigned short* __restrict__ out) {
  const int row = blockIdx.x;
  const size_t base = (size_t)row * D_ + threadIdx.x * 8;
  float4 a0 = *(const float4*)(p0 + base), a1 = *(const float4*)(p0 + base + 4);
  float4 b0 = *(const float4*)(p1 + base), b1 = *(const float4*)(p1 + base + 4);
  float4 c0 = *(const float4*)(hs + base), c1 = *(const float4*)(hs + base + 4);
  float4 va, vb;
  va.x = a0.x + b0.x + c0.x; va.y = a0.y + b0.y + c0.y;
  va.z = a0.z + b0.z + c0.z; va.w = a0.w + b0.w + c0.w;
  vb.x = a1.x + b1.x + c1.x; vb.y = a1.y + b1.y + c1.y;
  vb.z = a1.z + b1.z + c1.z; vb.w = a1.w + b1.w + c1.w;
  *(float4*)(hidden + base) = va;
  *(float4*)(hidden + base + 4) = vb;
  float ss = va.x*va.x + va.y*va.y + va.z*va.z + va.w*va.w
           + vb.x*vb.x + vb.y*vb.y + vb.z*vb.z + vb.w*vb.w;
  #pragma unroll
  for (int m = 1; m < 64; m <<= 1) ss += __shfl_xor(ss, m);
  __shared__ float red[4];
  if ((threadIdx.x & 63) == 0) red[threadIdx.x >> 6] = ss;
  __syncthreads();
  ss = red[0] + red[1] + red[2] + red[3];
  const float sc = rsqrtf(ss * (1.0f / D_) + EPS_);
  const int t8 = threadIdx.x * 8;
  float4 wa = *(const float4*)(w + t8);
  float4 wb = *(const float4*)(w + t8 + 4);
  bf16x8 ov;
  ov[0] = (short)f2bf(va.x * sc * wa.x); ov[1] = (short)f2bf(va.y * sc * wa.y);
  ov[2] = (short)f2bf(va.z * sc * wa.z); ov[3] = (short)f2bf(va.w * sc * wa.w);
  ov[4] = (short)f2bf(vb.x * sc * wb.x); ov[5] = (short)f2bf(vb.y * sc * wb.y);
  ov[6] = (short)f2bf(vb.z * sc * wb.z); ov[7] = (short)f2bf(vb.w * sc * wb.w);
  *(bf16x8*)(out + (size_t)row * D_ + t8) = ov;
}

// ---------------------------------------------------------------------------
// Final: d_out = p0 + p1 + hidden  (Wd split-K combine + residual), float4.
// ---------------------------------------------------------------------------
__global__ __launch_bounds__(256) void k_finaladd(const float* __restrict__ p0,
                                                  const float* __restrict__ p1,
                                                  const float* __restrict__ hidden,
                                                  float* __restrict__ out) {
  const size_t i = ((size_t)blockIdx.x * 256 + threadIdx.x) * 4;
  float4 a = *(const float4*)(p0 + i);
  float4 b = *(const float4*)(p1 + i);
  float4 c = *(const float4*)(hidden + i);
  float4 o;
  o.x = a.x + b.x + c.x; o.y = a.y + b.y + c.y;
  o.z = a.z + b.z + c.z; o.w = a.w + b.w + c.w;
  *(float4*)(out + i) = o;
}

// ---------------------------------------------------------------------------
// Weight transpose+convert: W (K,N) fp32 row-major -> Wt (N,K) bf16 row-major.
// ---------------------------------------------------------------------------
__global__ __launch_bounds__(256) void k_wtrans(const float* __restrict__ W,
                                                unsigned short* __restrict__ Wt,
                                                int K, int N) {
  __shared__ float tile[32][33];
  const int n0 = blockIdx.x * 32, k0 = blockIdx.y * 32;
  {
    const int kl = threadIdx.x >> 3, nc = (threadIdx.x & 7) * 4;
    float4 f = *(const float4*)(W + (size_t)(k0 + kl) * N + n0 + nc);
    tile[kl][nc] = f.x; tile[kl][nc + 1] = f.y;
    tile[kl][nc + 2] = f.z; tile[kl][nc + 3] = f.w;
  }
  __syncthreads();
  const int nl = threadIdx.x >> 3, kc = (threadIdx.x & 7) * 4;
  ushort4 o;
  o.x = f2bf(tile[kc][nl]);     o.y = f2bf(tile[kc + 1][nl]);
  o.z = f2bf(tile[kc + 2][nl]); o.w = f2bf(tile[kc + 3][nl]);
  *(ushort4*)(Wt + (size_t)(n0 + nl) * K + k0 + kc) = o;
}

// ---------------------------------------------------------------------------
// GEMM: C(M,N) = A(M,K) @ Bt(N,K)^T, bf16 in, fp32 accum.
// 256x128 tile, BK=32, 512 thr (8 waves 4x2), per-wave 64x64 out (4x4 frags).
// 3 LDS slots x 24KB (72KB, 2 blocks/CU); depth-2 prefetch, counted vmcnt(3),
// ONE barrier per K-step; ds_read -> MFMA waits left to the compiler;
// setprio(1) around the MFMA cluster. T2 swizzle via pre-swizzled global
// source. GROUP_M=4.
// EPI=0: bf16 out. EPI=2: bf16 = silu(gmul)*acc. EPI=3: fp32 partial (splitK).
// ---------------------------------------------------------------------------
template <int EPI>
__global__ __launch_bounds__(512, 4) void k_gemm(const unsigned short* __restrict__ A,
                                                 const unsigned short* __restrict__ Bt,
                                                 void* __restrict__ Cp,
                                                 const unsigned short* __restrict__ gmul,
                                                 int M, int ldc, int K) {
  __shared__ __align__(16) char lds[3 * 24576];   // slot s: A@s*24576 (16KB), B@+16384 (8KB)
  const int tid = threadIdx.x, lane = tid & 63, wave = tid >> 6;
  const int wm = wave >> 1, wn = wave & 1;

  // tile mapping: XCD bijective chunk + GROUP_M=4 column-major groups.
  const int nbx = (int)gridDim.x;
  const int nwg = nbx * (int)gridDim.y;
  int bid = (int)blockIdx.y * nbx + (int)blockIdx.x;
  bid = (bid & 7) * (nwg >> 3) + (bid >> 3);
  const int glen = 4 * nbx;
  const int gid = bid / glen, rem = bid - gid * glen;
  const int row0 = (gid * 4 + (rem & 3)) * 256;
  const int col0 = (rem >> 2) * 128;

  const int kz = (int)blockIdx.z;
  const int Klocal = K / (int)gridDim.z;
  const int kbeg = kz * Klocal;
  const int NK = Klocal / 32;

  // staging map: A call i in {0,1}: LDS byte i*8192 + wave*1024 + l*16
  //  -> row r = i*128 + wave*16 + (l>>2), phys col-byte (l&3)*16 (64B rows).
  // B: one call, rows 0..127. Logical k-elem pre-XORed (T2 swizzle).
  const int srow = wave * 16 + (lane >> 2);
  const int selem = (((lane & 3) ^ ((lane >> 3) & 3)) << 3);
  const unsigned short* pa = A  + (size_t)(row0 + srow) * K + kbeg + selem;
  const unsigned short* pb = Bt + (size_t)(col0 + srow) * K + kbeg + selem;
  const size_t rstep = (size_t)128 * K;
  char* const l = (char*)lds;
  const int woff = wave * 1024;

  f32x4 acc[4][4];
  #pragma unroll
  for (int i = 0; i < 4; i++)
    #pragma unroll
    for (int j = 0; j < 4; j++) acc[i][j] = {0.f, 0.f, 0.f, 0.f};

  auto STAGE = [&](int t, int slot) {
    char* s = l + slot * 24576;
    const unsigned short* a = pa + (size_t)t * 32;
    const unsigned short* b = pb + (size_t)t * 32;
    gload_lds16(a,         s + woff);
    gload_lds16(a + rstep, s + 8192 + woff);
    gload_lds16(b,         s + 16384 + woff);
  };

  // prologue: stage tiles 0,1 (3 loads each)
  STAGE(0, 0);
  STAGE(1, 1);

  // fragment read addressing (T2-swizzled): row-byte-width 64 in both A and B
  const int rdcb = (((lane >> 4) ^ ((lane >> 1) & 3)) << 4);
  const int arow0 = wm * 64 + (lane & 15);
  const int brow0 = wn * 64 + (lane & 15);

  int cur = 0, stg = 2;   // read slot = t%3, stage slot = (t+2)%3
  for (int t = 0; t < NK; ++t) {
    if (t + 2 < NK) {
      asm volatile("s_waitcnt vmcnt(3)" ::: "memory");   // STAGE(t) landed
    } else {
      asm volatile("s_waitcnt vmcnt(0)" ::: "memory");   // tail: drain all
    }
    __builtin_amdgcn_sched_barrier(0);
    __builtin_amdgcn_s_barrier();   // all waves: STAGE(t) landed; reads of
                                    // slot (t+2)%3 (iter t-1) retired.
    __builtin_amdgcn_sched_barrier(0);   // no hoisting reads above barrier
    const char* sa = l + cur * 24576;
    const char* sb = sa + 16384;
    bf16x8 af[4], bfr[4];
    #pragma unroll
    for (int mi = 0; mi < 4; mi++)
      af[mi] = *(const bf16x8*)(sa + (arow0 + mi * 16) * 64 + rdcb);
    #pragma unroll
    for (int ni = 0; ni < 4; ni++)
      bfr[ni] = *(const bf16x8*)(sb + (brow0 + ni * 16) * 64 + rdcb);
    if (t + 2 < NK) STAGE(t + 2, stg);
    // ds_read -> MFMA waits: compiler-inserted fine-grained lgkmcnt.
    __builtin_amdgcn_s_setprio(1);
    #pragma unroll
    for (int mi = 0; mi < 4; mi++)
      #pragma unroll
      for (int ni = 0; ni < 4; ni++)
        acc[mi][ni] = __builtin_amdgcn_mfma_f32_16x16x32_bf16(af[mi], bfr[ni],
                                                              acc[mi][ni], 0, 0, 0);
    __builtin_amdgcn_s_setprio(0);
    cur = (cur == 2) ? 0 : cur + 1;
    stg = (stg == 2) ? 0 : stg + 1;
  }

  const int crow = row0 + wm * 64 + ((lane >> 4) * 4);
  const int ccol = col0 + wn * 64 + (lane & 15);
  #pragma unroll
  for (int mi = 0; mi < 4; mi++)
    #pragma unroll
    for (int ni = 0; ni < 4; ni++) {
      const int r = crow + mi * 16;
      const int c = ccol + ni * 16;
      if constexpr (EPI == 0) {
        unsigned short* C = (unsigned short*)Cp;
        #pragma unroll
        for (int j = 0; j < 4; j++) C[(size_t)(r + j) * ldc + c] = f2bf(acc[mi][ni][j]);
      } else if constexpr (EPI == 2) {
        unsigned short* C = (unsigned short*)Cp;
        #pragma unroll
        for (int j = 0; j < 4; j++) {
          const float gx = bf2f(gmul[(size_t)(r + j) * ldc + c]);
          C[(size_t)(r + j) * ldc + c] = f2bf(gx / (1.f + __expf(-gx)) * acc[mi][ni][j]);
        }
      } else {
        float* C = (float*)Cp + (size_t)kz * M * ldc;
        #pragma unroll
        for (int j = 0; j < 4; j++) C[(size_t)(r + j) * ldc + c] = acc[mi][ni][j];
      }
    }
}

// ---------------------------------------------------------------------------
// Per-head RMSNorm + RoPE from the fused QKV buffer (row stride 4096).
// ---------------------------------------------------------------------------
template <int ISQ>
__global__ __launch_bounds__(256) void k_qknorm(const unsigned short* __restrict__ qkv,
                                                const float* __restrict__ nw,
                                                const float* __restrict__ cosT,
                                                const float* __restrict__ sinT,
                                                unsigned short* __restrict__ out) {
  const int NH = ISQ ? H_ : HKV_;
  const int HOFF = ISQ ? 0 : H_;
  const int r = blockIdx.x * 16 + (threadIdx.x >> 4);
  const int l16 = threadIdx.x & 15;
  const int hd0 = l16 * 8;
  const int b = r / (T_ * NH), rem = r % (T_ * NH);
  const int t = rem / NH, hh = rem % NH;
  bf16x8 v = *(const bf16x8*)(qkv + (size_t)(b * T_ + t) * QKVW_ + (HOFF + hh) * HD_ + hd0);
  float f[8];
  float ss = 0.f;
  #pragma unroll
  for (int j = 0; j < 8; j++) { f[j] = bf2f((unsigned short)v[j]); ss += f[j] * f[j]; }
  #pragma unroll
  for (int m = 1; m < 16; m <<= 1) ss += __shfl_xor(ss, m);
  const float sc = rsqrtf(ss * (1.0f / HD_) + EPS_);
  float4 wa = *(const float4*)(nw + hd0);
  float4 wb = *(const float4*)(nw + hd0 + 4);
  float nv[8];
  nv[0] = f[0] * sc * wa.x; nv[1] = f[1] * sc * wa.y;
  nv[2] = f[2] * sc * wa.z; nv[3] = f[3] * sc * wa.w;
  nv[4] = f[4] * sc * wb.x; nv[5] = f[5] * sc * wb.y;
  nv[6] = f[6] * sc * wb.z; nv[7] = f[7] * sc * wb.w;
  const float sgn = (hd0 < 64) ? -1.f : 1.f;
  float rot[8];
  #pragma unroll
  for (int j = 0; j < 8; j++) rot[j] = sgn * __shfl_xor(nv[j], 8);
  const float* cr = cosT + (size_t)t * HD_ + hd0;
  const float* sr = sinT + (size_t)t * HD_ + hd0;
  float4 ca = *(const float4*)cr, cb = *(const float4*)(cr + 4);
  float4 sa = *(const float4*)sr, sb = *(const float4*)(sr + 4);
  const float cv[8] = {ca.x, ca.y, ca.z, ca.w, cb.x, cb.y, cb.z, cb.w};
  const float sv[8] = {sa.x, sa.y, sa.z, sa.w, sb.x, sb.y, sb.z, sb.w};
  bf16x8 ov;
  #pragma unroll
  for (int j = 0; j < 8; j++) ov[j] = (short)f2bf(nv[j] * cv[j] + rot[j] * sv[j]);
  if (ISQ) *(bf16x8*)(out + (((size_t)b * H_ + hh) * T_ + t) * HD_ + hd0) = ov;
  else     *(bf16x8*)(out + (((size_t)b * HKV_ + hh) * TK_ + R_ + t) * HD_ + hd0) = ov;
}

// ---------------------------------------------------------------------------
// Virtual K rows: k_all[.., 0..R-1, ..] = k_extra * eff  (eff = 0.5*sigmoid(a))
// ---------------------------------------------------------------------------
__global__ __launch_bounds__(256) void k_kvirt(const float* __restrict__ ke,
                                               const float* __restrict__ alog,
                                               unsigned short* __restrict__ k_all) {
  const size_t i = (size_t)blockIdx.x * 256 + threadIdx.x;  // B*HKV*R*HD = 262144
  const float eff = 0.5f / (1.f + __expf(-alog[0]));
  const int hd = (int)(i & 127);
  const int r  = (int)((i >> 7) & 127);
  const int bk = (int)(i >> 14);
  k_all[((size_t)bk * TK_ + r) * HD_ + hd] = f2bf(ke[i] * eff);
}

// ---------------------------------------------------------------------------
// Build v_allT, key-tiled: (B,HKV, NT64, HD, 64key) bf16 from [v_extra*eff ; v].
// Key columns inside each 64-tile PERMUTED to the PV register k-order.
// ---------------------------------------------------------------------------
__global__ __launch_bounds__(256) void k_vbuild(const unsigned short* __restrict__ qkv,
                                                const float* __restrict__ ve,
                                                const float* __restrict__ alog,
                                                unsigned short* __restrict__ vT) {
  __shared__ float tile[32][33];
  const int kt = blockIdx.x, ht = blockIdx.y, bk = blockIdx.z;
  const int b = bk >> 3, kvh = bk & 7;
  const float eff = 0.5f / (1.f + __expf(-alog[0]));
  const int kl = threadIdx.x >> 3, hc = (threadIdx.x & 7) * 4;
  const int key = kt * 32 + kl, hd0 = ht * 32;
  if (key < R_) {
    float4 f = *(const float4*)(ve + (((size_t)(b * HKV_ + kvh) * R_ + key) * HD_ + hd0 + hc));
    tile[kl][hc] = f.x * eff; tile[kl][hc + 1] = f.y * eff;
    tile[kl][hc + 2] = f.z * eff; tile[kl][hc + 3] = f.w * eff;
  } else {
    const unsigned short* s = qkv + (size_t)(b * T_ + key - R_) * QKVW_
                              + (H_ + HKV_ + kvh) * HD_ + hd0 + hc;
    ushort4 u = *(const ushort4*)s;
    tile[kl][hc] = bf2f(u.x); tile[kl][hc + 1] = bf2f(u.y);
    tile[kl][hc + 2] = bf2f(u.z); tile[kl][hc + 3] = bf2f(u.w);
  }
  __syncthreads();
  const int hl = threadIdx.x >> 3, kc = (threadIdx.x & 7) * 4;
  ushort4 o;
  o.x = f2bf(tile[kc][hl]);     o.y = f2bf(tile[kc + 1][hl]);
  o.z = f2bf(tile[kc + 2][hl]); o.w = f2bf(tile[kc + 3][hl]);
  const int c0 = (kt & 1) * 32 + kc;
  const int p0 = ((c0 >> 5) << 5) | (((c0 >> 2) & 3) << 3) | (((c0 >> 4) & 1) << 2);
  *(ushort4*)(vT + ((size_t)bk * NT64_ + (kt >> 1)) * (HD_ * 64)
                  + (size_t)(hd0 + hl) * 64 + p0) = o;
}

// ---------------------------------------------------------------------------
// Flash attention. 256 thr (4 waves), 128 q-rows/block (32/wave), 64-key tiles.
// Swapped QK^T; P stays in registers; double-buffered K/V via global_load_lds.
// ---------------------------------------------------------------------------
__global__ __launch_bounds__(256, 2) void k_attn(const unsigned short* __restrict__ qr,
                                                 const unsigned short* __restrict__ k_all,
                                                 const unsigned short* __restrict__ vT,
                                                 unsigned short* __restrict__ out) {
  __shared__ __align__(16) unsigned short kT[2][64 * 128];
  __shared__ __align__(16) unsigned short vS[2][128 * 64];
  const int tid = threadIdx.x, lane = tid & 63, w = tid >> 6;
  const int qb = (int)gridDim.x - 1 - (int)blockIdx.x;
  const int h = blockIdx.y, b = blockIdx.z;
  const int kvh = h >> 1;
  const int q0 = qb * 128;

  bf16x8 qf[2][4];
  #pragma unroll
  for (int fq = 0; fq < 2; fq++) {
    const unsigned short* qbase =
        qr + ((size_t)((b * H_ + h) * T_) + q0 + w * 32 + fq * 16 + (lane & 15)) * HD_ + (lane >> 4) * 8;
    #pragma unroll
    for (int kc = 0; kc < 4; kc++) qf[fq][kc] = *(const bf16x8*)(qbase + kc * 32);
  }

  f32x4 zero = {0.f, 0.f, 0.f, 0.f};
  f32x4 o[2][8];
  #pragma unroll
  for (int fq = 0; fq < 2; fq++)
    #pragma unroll
    for (int i = 0; i < 8; i++) o[fq][i] = zero;
  float mrow[2] = {-3e38f, -3e38f}, lrow[2] = {0.f, 0.f};

  const int kr0 = w * 4 + (lane >> 4);
  const char* kSrc = (const char*)(k_all + (size_t)(b * HKV_ + kvh) * TK_ * HD_)
                     + (size_t)kr0 * 256 + (((lane & 15) * 16) ^ ((kr0 & 7) << 4));
  const char* vSrc = (const char*)(vT + (size_t)(b * HKV_ + kvh) * NT64_ * HD_ * 64)
                     + (size_t)(w * 8 + (lane >> 3)) * 128
                     + (((lane & 7) * 16) ^ (((lane >> 3) & 7) << 4));
  char* kL = (char*)kT;
  char* vL = (char*)vS;
  const int ldsw = w * 1024;

  const int ntiles = 2 * qb + 4;
  #pragma unroll
  for (int i = 0; i < 4; i++) {
    gload_lds16(kSrc + i * 4096, kL + ldsw + i * 4096);
    gload_lds16(vSrc + i * 4096, vL + ldsw + i * 4096);
  }
  int cur = 0;

  for (int it = 0; it < ntiles; ++it) {
    __syncthreads();
    if (it + 1 < ntiles) {
      const char* ks = kSrc + (size_t)(it + 1) * 16384;
      const char* vs = vSrc + (size_t)(it + 1) * 16384;
      char* kd = kL + ((cur ^ 1) * 16384 + ldsw);
      char* vd = vL + ((cur ^ 1) * 16384 + ldsw);
      #pragma unroll
      for (int i = 0; i < 4; i++) {
        gload_lds16(ks + i * 4096, kd + i * 4096);
        gload_lds16(vs + i * 4096, vd + i * 4096);
      }
    }
    const char* kTc = kL + cur * 16384;
    const char* vSc = vL + cur * 16384;

    f32x4 s[2][4];
    #pragma unroll
    for (int ni = 0; ni < 4; ni++) { s[0][ni] = zero; s[1][ni] = zero; }
    #pragma unroll
    for (int ni = 0; ni < 4; ni++) {
      const int rk = ni * 16 + (lane & 15);
      const int swz = (rk & 7) << 4;
      #pragma unroll
      for (int kc = 0; kc < 4; kc++) {
        bf16x8 kf = *(const bf16x8*)(kTc + ((rk * 256 + kc * 64 + (lane >> 4) * 16) ^ swz));
        s[0][ni] = __builtin_amdgcn_mfma_f32_16x16x32_bf16(kf, qf[0][kc], s[0][ni], 0, 0, 0);
        s[1][ni] = __builtin_amdgcn_mfma_f32_16x16x32_bf16(kf, qf[1][kc], s[1][ni], 0, 0, 0);
      }
    }

    const bool domask = (it >= ntiles - 2);
    bf16x8 pa[2][2];
    #pragma unroll
    for (int fq = 0; fq < 2; fq++) {
      const int q = q0 + w * 32 + fq * 16 + (lane & 15);
      #pragma unroll
      for (int ni = 0; ni < 4; ni++)
        #pragma unroll
        for (int j = 0; j < 4; j++) {
          float v = s[fq][ni][j] * SCALING_;
          if (domask) {
            const int key = it * 64 + ni * 16 + (lane >> 4) * 4 + j;
            if (key > R_ + q) v = -3e38f;
          }
          s[fq][ni][j] = v;
        }
      float pm = -3e38f;
      #pragma unroll
      for (int ni = 0; ni < 4; ni++)
        #pragma unroll
        for (int j = 0; j < 4; j++) pm = fmaxf(pm, s[fq][ni][j]);
      pm = fmaxf(pm, __shfl_xor(pm, 16));
      pm = fmaxf(pm, __shfl_xor(pm, 32));
      const float mn = fmaxf(mrow[fq], pm);
      const float scl = __expf(mrow[fq] - mn);
      mrow[fq] = mn;
      float rs = 0.f;
      #pragma unroll
      for (int ni = 0; ni < 4; ni++)
        #pragma unroll
        for (int j = 0; j < 4; j++) {
          const float p = __expf(s[fq][ni][j] - mn);
          s[fq][ni][j] = p;
          rs += p;
        }
      rs += __shfl_xor(rs, 16);
      rs += __shfl_xor(rs, 32);
      lrow[fq] = lrow[fq] * scl + rs;
      #pragma unroll
      for (int kc2 = 0; kc2 < 2; kc2++) {
        bf16x8 t;
        #pragma unroll
        for (int j = 0; j < 4; j++) {
          t[j]     = (short)f2bf(s[fq][2 * kc2][j]);
          t[4 + j] = (short)f2bf(s[fq][2 * kc2 + 1][j]);
        }
        pa[fq][kc2] = t;
      }
      #pragma unroll
      for (int j = 0; j < 4; j++) {
        const float sj = __shfl(scl, (lane & 48) | (((lane >> 4) << 2) + j));
        #pragma unroll
        for (int ni = 0; ni < 8; ni++) o[fq][ni][j] *= sj;
      }
    }

    #pragma unroll
    for (int kc2 = 0; kc2 < 2; kc2++) {
      #pragma unroll
      for (int ni = 0; ni < 8; ni++) {
        const int rv = ni * 16 + (lane & 15);
        bf16x8 vb = *(const bf16x8*)(vSc + ((rv * 128 + kc2 * 64 + (lane >> 4) * 16) ^ ((rv & 7) << 4)));
        o[0][ni] = __builtin_amdgcn_mfma_f32_16x16x32_bf16(pa[0][kc2], vb, o[0][ni], 0, 0, 0);
        o[1][ni] = __builtin_amdgcn_mfma_f32_16x16x32_bf16(pa[1][kc2], vb, o[1][ni], 0, 0, 0);
      }
    }
    cur ^= 1;
  }

  #pragma unroll
  for (int fq = 0; fq < 2; fq++) {
    float linv[4];
    #pragma unroll
    for (int j = 0; j < 4; j++)
      linv[j] = 1.f / __shfl(lrow[fq], (lane & 48) | (((lane >> 4) << 2) + j));
    const size_t orow = ((size_t)b * T_ + q0 + w * 32 + fq * 16 + (lane >> 4) * 4) * (H_ * HD_)
                        + h * HD_ + (lane & 15);
    #pragma unroll
    for (int ni = 0; ni < 8; ni++)
      #pragma unroll
      for (int j = 0; j < 4; j++)
        out[orow + (size_t)j * (H_ * HD_) + ni * 16] = f2bf(o[fq][ni][j] * linv[j]);
  }
}

// ===========================================================================
extern "C" void kernel_launch(void* const* d_in, const int* in_sizes, int n_in,
                              void* d_out, int out_size, void* d_ws, size_t ws_size,
                              hipStream_t stream) {
  const float* hs   = (const float*)d_in[0];
  const float* ke   = (const float*)d_in[1];
  const float* ve   = (const float*)d_in[2];
  const float* cosT = (const float*)d_in[3];
  const float* sinT = (const float*)d_in[4];
  // d_in[5] = attention_mask: deterministic causal, applied analytically.
  const float* alog = (const float*)d_in[6];
  const float* Wq   = (const float*)d_in[7];
  const float* Wk   = (const float*)d_in[8];
  const float* Wv   = (const float*)d_in[9];
  const float* Wo   = (const float*)d_in[10];
  const float* qnw  = (const float*)d_in[11];
  const float* knw  = (const float*)d_in[12];
  const float* ln1  = (const float*)d_in[13];
  const float* ln2  = (const float*)d_in[14];
  const float* Wg   = (const float*)d_in[15];
  const float* Wu   = (const float*)d_in[16];
  const float* Wd   = (const float*)d_in[17];

  char* ws = (char*)d_ws;
  size_t off = 0;
  auto alloc = [&](size_t bytes) {
    void* p = ws + off;
    off += (bytes + 255) & ~(size_t)255;
    return p;
  };
  const int M = B_ * T_;  // 4096
  unsigned short* h     = (unsigned short*)alloc((size_t)M * D_ * 2);
  unsigned short* wt    = (unsigned short*)alloc((size_t)DFF_ * D_ * 2);
  unsigned short* qkv   = (unsigned short*)alloc((size_t)M * QKVW_ * 2);
  unsigned short* qrope = (unsigned short*)alloc((size_t)B_ * H_ * T_ * HD_ * 2);
  unsigned short* kall  = (unsigned short*)alloc((size_t)B_ * HKV_ * TK_ * HD_ * 2);
  unsigned short* vallT = (unsigned short*)alloc((size_t)B_ * HKV_ * (size_t)NT64_ * HD_ * 64 * 2);
  unsigned short* attno = (unsigned short*)alloc((size_t)M * 2048 * 2);
  float*          hidden= (float*)alloc((size_t)M * D_ * 4);
  unsigned short* g     = (unsigned short*)alloc((size_t)M * DFF_ * 2);
  // split-K partial stack (2 x M x 2048 fp32 = 67.1M), aliasing dead buffers.
  float* part = (float*)qkv;

  // 1) input layernorm
  k_rmsnorm<<<M, 256, 0, stream>>>(hs, ln1, h);
  // 2) fused QKV projection (N=4096)
  k_wtrans<<<dim3(2048 / 32, 2048 / 32), 256, 0, stream>>>(Wq, wt, 2048, 2048);
  k_wtrans<<<dim3(1024 / 32, 2048 / 32), 256, 0, stream>>>(Wk, wt + (size_t)2048 * 2048, 2048, 1024);
  k_wtrans<<<dim3(1024 / 32, 2048 / 32), 256, 0, stream>>>(Wv, wt + (size_t)3072 * 2048, 2048, 1024);
  k_gemm<0><<<dim3(QKVW_ / 128, M / 256), 512, 0, stream>>>(h, wt, qkv, nullptr, M, QKVW_, 2048);
  // 3) head norms + RoPE + virtual KV
  k_qknorm<1><<<(B_ * T_ * H_) / 16, 256, 0, stream>>>(qkv, qnw, cosT, sinT, qrope);
  k_qknorm<0><<<(B_ * T_ * HKV_) / 16, 256, 0, stream>>>(qkv, knw, cosT, sinT, kall);
  k_kvirt<<<(B_ * HKV_ * R_ * HD_) / 256, 256, 0, stream>>>(ke, alog, kall);
  k_vbuild<<<dim3(TK_ / 32, HD_ / 32, B_ * HKV_), 256, 0, stream>>>(qkv, ve, alog, vallT);
  // 4) attention
  k_attn<<<dim3(T_ / 128, H_, B_), 256, 0, stream>>>(qrope, kall, vallT, attno);
  // 5) output projection, split-K=2 -> fp32 partials
  k_wtrans<<<dim3(2048 / 32, 2048 / 32), 256, 0, stream>>>(Wo, wt, 2048, 2048);
  k_gemm<3><<<dim3(2048 / 128, M / 256, 2), 512, 0, stream>>>(attno, wt, part, nullptr, M, 2048, 2048);
  // 6) combine partials + residual + post-attn layernorm
  k_rms2<<<M, 256, 0, stream>>>(part, part + (size_t)M * 2048, hs, ln2, hidden, h);
  // 7) SwiGLU MLP (silu*u fused into the Wu GEMM epilogue)
  k_wtrans<<<dim3(DFF_ / 32, 2048 / 32), 256, 0, stream>>>(Wg, wt, 2048, DFF_);
  k_gemm<0><<<dim3(DFF_ / 128, M / 256), 512, 0, stream>>>(h, wt, g, nullptr, M, DFF_, 2048);
  k_wtrans<<<dim3(DFF_ / 32, 2048 / 32), 256, 0, stream>>>(Wu, wt, 2048, DFF_);
  k_gemm<2><<<dim3(DFF_ / 128, M / 256), 512, 0, stream>>>(h, wt, g, g, M, DFF_, 2048);
  // 8) down projection, split-K=2 -> partials; final add with residual
  k_wtrans<<<dim3(2048 / 32, DFF_ / 32), 256, 0, stream>>>(Wd, wt, DFF_, 2048);
  k_gemm<3><<<dim3(2048 / 128, M / 256, 2), 512, 0, stream>>>(g, wt, part, nullptr, M, 2048, DFF_);
  k_finaladd<<<(M * 2048 / 4) / 256, 256, 0, stream>>>(part, part + (size_t)M * 2048, hidden, (float*)d_out);
}